// Round 22
// baseline (76.832 us; speedup 1.0000x reference)
//
#include <hip/hip_runtime.h>

// QuantizedLinear: out[t][o] = sum_k x[t][k] * (w_q[o][k]-128)*scale[o] + bias[o]
// M=16, N=8192, K=8192. Memory-bound on w_q (256 MB int32, read once).
//
// R22: drain-free deep pipeline (R21) x LDS-light geometry (W_O=4).
// R21's null traced to LDS co-saturation: LDS:HBM byte ratio = NT/W_O; at
// W_O=2 that's 8x = the ds_read capability ratio (85 B/cy / 10.25 B/cy) ->
// the x-broadcast pipe was the wall, masking the drain-free gain. W_O=4
// halves LDS pressure (ratio 4, ~25-50% load) while keeping the no-same-
// chunk-wait schedule: stage x TWO chunks ahead (NBUF=4), w prefetched ONE
// chunk ahead; FMA(c)'s operand wait = vmcnt(6) (leaves 6 newer loads
// flying, retires stage(c+1) exactly when needed); barrier waits ONLY
// lgkmcnt(0). No vmcnt drain anywhere in the loop.
// Register budget (R13 lesson): wpf = 4 x int2 = 8 VGPR/buffer (not R13's
// 32); live ~105 = acc 64 + wpf 16 + addr/misc, under the (256,2)/128 cap.
// Geometry: BLOCK=256, W_O=4, CH_PER_BLOCK=16, grid 512 (2 blocks/CU,
// 8 waves/CU), K_CHUNK=128, NBUF=4 -> LDS 32 KB.

#define IN_F   8192
#define OUT_F  8192
#define NT     16
#define BLOCK  256
#define W_O    4
#define CH_PER_BLOCK 16          // 4 waves * W_O
#define K_CHUNK 128
#define NCHUNK (IN_F / K_CHUNK)  // 64
#define NBUF   4

typedef float f32x2 __attribute__((ext_vector_type(2)));

__global__ __launch_bounds__(BLOCK, 2)
void qlin_kernel(const float* __restrict__ x,     // [16][8192]
                 const int*   __restrict__ w_q,   // [8192][8192]
                 const float* __restrict__ scale, // [8192]
                 const float* __restrict__ bias,  // [8192]
                 float* __restrict__ out)         // [16][8192]
{
    __shared__ float xs[NBUF][NT][K_CHUNK];       // 32 KB

    const int tid  = threadIdx.x;
    const int lane = tid & 63;
    const int wave = tid >> 6;
    const int o_base = blockIdx.x * CH_PER_BLOCK + wave * W_O;

    const int* __restrict__ wr0 = w_q + (size_t)(o_base + 0) * IN_F;
    const int* __restrict__ wr1 = w_q + (size_t)(o_base + 1) * IN_F;
    const int* __restrict__ wr2 = w_q + (size_t)(o_base + 2) * IN_F;
    const int* __restrict__ wr3 = w_q + (size_t)(o_base + 3) * IN_F;

    // Stage x chunk c (8 KB = 16 rows x 512 B) into LDS buf b: 2 rounds x
    // 4 KB (256 thr x 16 B). Lane's global row = r*8 + wave*2 + (lane>>5),
    // byte (lane&31)*16; LDS dest wave-uniform base (+lane*16 by HW) is the
    // same flat offset -> linear layout, per global_load_lds contract.
#define STAGE(c, b)                                                          \
    {                                                                        \
        _Pragma("unroll")                                                    \
        for (int r = 0; r < 2; ++r) {                                        \
            const int row = r * 8 + wave * 2 + (lane >> 5);                  \
            const char* g = (const char*)x + (size_t)row * (IN_F * 4) +      \
                            (size_t)(c) * (K_CHUNK * 4) + (lane & 31) * 16;  \
            char* l = (char*)(&xs[0][0][0]) + (b) * (NT * K_CHUNK * 4) +     \
                      r * 4096 + wave * 1024;                                \
            __builtin_amdgcn_global_load_lds(                                \
                (const __attribute__((address_space(1))) void*)g,            \
                (__attribute__((address_space(3))) void*)l, 16, 0, 0);       \
        }                                                                    \
    }

    // Prefetch chunk c's four w int2 vectors (8 VGPRs).
#define WPF(P0, P1, P2, P3, c)                                               \
    P0 = *reinterpret_cast<const int2*>(wr0 + (c) * K_CHUNK + lane * 2);     \
    P1 = *reinterpret_cast<const int2*>(wr1 + (c) * K_CHUNK + lane * 2);     \
    P2 = *reinterpret_cast<const int2*>(wr2 + (c) * K_CHUNK + lane * 2);     \
    P3 = *reinterpret_cast<const int2*>(wr3 + (c) * K_CHUNK + lane * 2);

    // One 128-wide k-step from prefetched regs + LDS x (float2 per t).
#define FMA(P0, P1, P2, P3, b)                                               \
    {                                                                        \
        f32x2 wf[2][2];  /* wf[j2][e]: rows {2j2,2j2+1} at element e */      \
        wf[0][0] = (f32x2){(float)(P0.x - 128), (float)(P1.x - 128)};        \
        wf[0][1] = (f32x2){(float)(P0.y - 128), (float)(P1.y - 128)};        \
        wf[1][0] = (f32x2){(float)(P2.x - 128), (float)(P3.x - 128)};        \
        wf[1][1] = (f32x2){(float)(P2.y - 128), (float)(P3.y - 128)};        \
        _Pragma("unroll")                                                    \
        for (int t = 0; t < NT; ++t) {                                       \
            const float2 xv = *reinterpret_cast<const float2*>(              \
                &xs[b][t][lane * 2]);                                        \
            acc2[t][0] += wf[0][0] * (f32x2){xv.x, xv.x};                    \
            acc2[t][1] += wf[1][0] * (f32x2){xv.x, xv.x};                    \
            acc2[t][0] += wf[0][1] * (f32x2){xv.y, xv.y};                    \
            acc2[t][1] += wf[1][1] * (f32x2){xv.y, xv.y};                    \
        }                                                                    \
    }

    // Chunk: stage 2-ahead, prefetch 1-ahead (order pinned), compute from
    // chunk-old regs (operand wait vmcnt(6), auto-inserted), barrier with
    // lgkm-only wait. The load queue never empties.
#define CHUNK(c, A0, A1, A2, A3, B0, B1, B2, B3)                             \
    {                                                                        \
        if ((c) + 2 < NCHUNK) STAGE((c) + 2, ((c) + 2) & 3)                  \
        __builtin_amdgcn_sched_barrier(0);                                   \
        if ((c) + 1 < NCHUNK) { WPF(B0, B1, B2, B3, (c) + 1) }               \
        __builtin_amdgcn_sched_barrier(0);                                   \
        FMA(A0, A1, A2, A3, (c) & 3)                                         \
        __builtin_amdgcn_sched_barrier(0);                                   \
        if ((c) + 1 < NCHUNK) {                                              \
            asm volatile("s_waitcnt lgkmcnt(0)" ::: "memory");               \
            __builtin_amdgcn_s_barrier();                                    \
            __builtin_amdgcn_sched_barrier(0);                               \
        }                                                                    \
    }

    f32x2 acc2[NT][2];   // 64 VGPRs
#pragma unroll
    for (int t = 0; t < NT; ++t) {
        acc2[t][0] = (f32x2)0.0f;
        acc2[t][1] = (f32x2)0.0f;
    }

    int2 a0, a1, a2, a3, b0, b1, b2, b3;   // w prefetch (16 VGPRs)

    // prologue: stage(0)[2], stage(1)[2], wpf(0)[4]; vmcnt(6) retires
    // stage(0) only -- stage(1) + wpf(0) stay in flight across the barrier.
    STAGE(0, 0)
    __builtin_amdgcn_sched_barrier(0);
    STAGE(1, 1)
    __builtin_amdgcn_sched_barrier(0);
    WPF(a0, a1, a2, a3, 0)
    __builtin_amdgcn_sched_barrier(0);
    asm volatile("s_waitcnt vmcnt(6)" ::: "memory");
    __builtin_amdgcn_s_barrier();
    __builtin_amdgcn_sched_barrier(0);

#pragma unroll 1
    for (int cc = 0; cc < NCHUNK; cc += 2) {
        CHUNK(cc + 0, a0, a1, a2, a3, b0, b1, b2, b3)
        CHUNK(cc + 1, b0, b1, b2, b3, a0, a1, a2, a3)
    }

#undef STAGE
#undef WPF
#undef FMA
#undef CHUNK

    // ---- cross-lane reduction: 64 (t,j) values, 6-step butterfly each ----
    float myval = 0.0f;
#pragma unroll
    for (int t = 0; t < NT; ++t) {
#pragma unroll
        for (int j = 0; j < W_O; ++j) {
            float v = acc2[t][j >> 1][j & 1];
#pragma unroll
            for (int off = 32; off > 0; off >>= 1)
                v += __shfl_xor(v, off, 64);
            if (lane == (t * W_O + j)) myval = v;
        }
    }

    // lane l -> (t = l>>2, channel j = l&3)
    const int t_o = lane >> 2;
    const int o   = o_base + (lane & 3);
    out[(size_t)t_o * OUT_F + o] = myval * scale[o] + bias[o];
}

extern "C" void kernel_launch(void* const* d_in, const int* in_sizes, int n_in,
                              void* d_out, int out_size, void* d_ws, size_t ws_size,
                              hipStream_t stream) {
    const float* x     = (const float*)d_in[0];
    const int*   w_q   = (const int*)d_in[1];
    const float* scale = (const float*)d_in[2];
    const float* bias  = (const float*)d_in[3];
    float*       out   = (float*)d_out;

    dim3 grid(OUT_F / CH_PER_BLOCK);   // 512 blocks -> 2/CU, 8 waves/CU
    dim3 block(BLOCK);
    qlin_kernel<<<grid, block, 0, stream>>>(x, w_q, scale, bias, out);
}

// Round 23
// 75.489 us; speedup vs baseline: 1.0178x; 1.0178x over previous
//
#include <hip/hip_runtime.h>

// QuantizedLinear: out[t][o] = sum_k x[t][k] * (w_q[o][k]-128)*scale[o] + bias[o]
// M=16, N=8192, K=8192. Memory-bound on w_q (256 MB int32, read once).
//
// R23: cut HBM BYTES, not latency. Audit: device x-read demand = nblocks x
// 512 KB; at grid 512 that's 268 MB -- EQUAL to w -- and R10's FETCH=409MB
// shows ~half of it misses L3 (w stream thrashes the 256MB L3). At ~400MB
// actual traffic, R12's 64.6us = 6.2 TB/s = ~98% of achievable -- R12 was
// already at the roofline FOR ITS TRAFFIC. All scheduling fixes (R20-R22)
// failed because there was no latency gap to close. Levers here:
//  1. Block-level x amortization: BLOCK=512 (8 waves x W_O=4, CH=32),
//     grid 256 -> x demand halves to 134 MB (same staged chunk feeds 2x
//     the waves). LDS 64 KB, 16-barrier cadence (best measured).
//  2. Nontemporal w loads: w is stream-once; nt keeps it from evicting x
//     from L3 (R11's FETCH=145MB hints nt slashes fetch; it was spill-
//     confounded -- here VGPR live ~105 under the (512,1)/256 cap).
// Structure otherwise EXACTLY R12 (best, 64.6us): x via global_load_lds,
// double-buffered, raw s_barrier + lgkm-only wait, packed f32x2 FMA.

#define IN_F   8192
#define OUT_F  8192
#define NT     16
#define BLOCK  512
#define W_O    4
#define CH_PER_BLOCK 32          // 8 waves * W_O
#define K_CHUNK 512
#define NCHUNK (IN_F / K_CHUNK)  // 16

typedef float f32x2 __attribute__((ext_vector_type(2)));
typedef int   i4x   __attribute__((ext_vector_type(4)));

__global__ __launch_bounds__(BLOCK, 1)
void qlin_kernel(const float* __restrict__ x,     // [16][8192]
                 const int*   __restrict__ w_q,   // [8192][8192]
                 const float* __restrict__ scale, // [8192]
                 const float* __restrict__ bias,  // [8192]
                 float* __restrict__ out)         // [16][8192]
{
    __shared__ float xs[2][NT][K_CHUNK];          // 64 KB

    const int tid  = threadIdx.x;
    const int lane = tid & 63;
    const int wave = tid >> 6;
    const int o_base = blockIdx.x * CH_PER_BLOCK + wave * W_O;

    const i4x* __restrict__ wq0 = (const i4x*)(w_q + (size_t)(o_base + 0) * IN_F);
    const i4x* __restrict__ wq1 = (const i4x*)(w_q + (size_t)(o_base + 1) * IN_F);
    const i4x* __restrict__ wq2 = (const i4x*)(w_q + (size_t)(o_base + 2) * IN_F);
    const i4x* __restrict__ wq3 = (const i4x*)(w_q + (size_t)(o_base + 3) * IN_F);

    // Stage x chunk c (32 KB = 16 rows x 2048 B) into LDS buf b.
    // 4 rounds x 8 KB (512 thr x 16 B). flat = r*8192 + wave*1024 (+lane*16
    // by HW on LDS side, explicit on global side); row = r*4 + (wave>>1),
    // byte-in-row = (wave&1)*1024 + lane*16 -- each wave's 1 KB stays in one
    // 2048 B row; LDS layout linear per global_load_lds contract.
#define STAGE(c, b)                                                          \
    {                                                                        \
        _Pragma("unroll")                                                    \
        for (int r = 0; r < 4; ++r) {                                        \
            const int row = r * 4 + (wave >> 1);                             \
            const char* g = (const char*)x + (size_t)row * (IN_F * 4) +      \
                            (size_t)(c) * 2048 + (wave & 1) * 1024 +         \
                            lane * 16;                                       \
            char* l = (char*)(&xs[0][0][0]) + (b) * 32768 +                  \
                      r * 8192 + wave * 1024;                                \
            __builtin_amdgcn_global_load_lds(                                \
                (const __attribute__((address_space(1))) void*)g,            \
                (__attribute__((address_space(3))) void*)l, 16, 0, 0);       \
        }                                                                    \
    }

    f32x2 acc2[NT][2];   // acc2[t][j2][e] = acc[t][j2*2+e]; 64 VGPRs
#pragma unroll
    for (int t = 0; t < NT; ++t) {
        acc2[t][0] = (f32x2)0.0f;
        acc2[t][1] = (f32x2)0.0f;
    }

    // prologue: stage chunk 0, full wait (nothing else in flight)
    STAGE(0, 0)
    __builtin_amdgcn_sched_barrier(0);
    asm volatile("s_waitcnt vmcnt(0)" ::: "memory");
    __builtin_amdgcn_s_barrier();
    __builtin_amdgcn_sched_barrier(0);

#pragma unroll 1
    for (int c = 0; c < NCHUNK; ++c) {
        const int cur = c & 1;

        if (c + 1 < NCHUNK) STAGE(c + 1, cur ^ 1)   // oldest vmem this chunk
        __builtin_amdgcn_sched_barrier(0);

        // ---- compute chunk c: 2 k-steps; nt w-loads (vmcnt), x LDS ----
#pragma unroll
        for (int ks = 0; ks < K_CHUNK / 256; ++ks) {
            const int kl = ks * 256 + lane * 4;          // within chunk
            const int kq = c * (K_CHUNK / 4) + ks * 64 + lane;  // int4 idx
            const i4x w0 = __builtin_nontemporal_load(wq0 + kq);
            const i4x w1 = __builtin_nontemporal_load(wq1 + kq);
            const i4x w2 = __builtin_nontemporal_load(wq2 + kq);
            const i4x w3 = __builtin_nontemporal_load(wq3 + kq);

            f32x2 wf[2][4];  // wf[j2][e] = { rows 2j2, 2j2+1 } at element e
#pragma unroll
            for (int e = 0; e < 4; ++e) {
                wf[0][e] = (f32x2){(float)(w0[e] - 128), (float)(w1[e] - 128)};
                wf[1][e] = (f32x2){(float)(w2[e] - 128), (float)(w3[e] - 128)};
            }

#pragma unroll
            for (int t = 0; t < NT; ++t) {
                const float4 xv = *reinterpret_cast<const float4*>(
                    &xs[cur][t][kl]);
                acc2[t][0] += wf[0][0] * (f32x2){xv.x, xv.x};
                acc2[t][1] += wf[1][0] * (f32x2){xv.x, xv.x};
                acc2[t][0] += wf[0][1] * (f32x2){xv.y, xv.y};
                acc2[t][1] += wf[1][1] * (f32x2){xv.y, xv.y};
                acc2[t][0] += wf[0][2] * (f32x2){xv.z, xv.z};
                acc2[t][1] += wf[1][2] * (f32x2){xv.z, xv.z};
                acc2[t][0] += wf[0][3] * (f32x2){xv.w, xv.w};
                acc2[t][1] += wf[1][3] * (f32x2){xv.w, xv.w};
            }
        }

        // barrier: raw, lgkm-only (R12-proven). FMA consumption of this
        // chunk's w (youngest) already implied stage(c+1) retirement.
        __builtin_amdgcn_sched_barrier(0);
        asm volatile("s_waitcnt lgkmcnt(0)" ::: "memory");
        __builtin_amdgcn_s_barrier();
        __builtin_amdgcn_sched_barrier(0);
    }
#undef STAGE

    // ---- cross-lane reduction: 64 (t,j) values, 6-step butterfly each ----
    float myval = 0.0f;
#pragma unroll
    for (int t = 0; t < NT; ++t) {
#pragma unroll
        for (int j = 0; j < W_O; ++j) {
            float v = acc2[t][j >> 1][j & 1];
#pragma unroll
            for (int off = 32; off > 0; off >>= 1)
                v += __shfl_xor(v, off, 64);
            if (lane == (t * W_O + j)) myval = v;
        }
    }

    // lane l -> (t = l>>2, channel j = l&3)
    const int t_o = lane >> 2;
    const int o   = o_base + (lane & 3);
    out[(size_t)t_o * OUT_F + o] = myval * scale[o] + bias[o];
}

extern "C" void kernel_launch(void* const* d_in, const int* in_sizes, int n_in,
                              void* d_out, int out_size, void* d_ws, size_t ws_size,
                              hipStream_t stream) {
    const float* x     = (const float*)d_in[0];
    const int*   w_q   = (const int*)d_in[1];
    const float* scale = (const float*)d_in[2];
    const float* bias  = (const float*)d_in[3];
    float*       out   = (float*)d_out;

    dim3 grid(OUT_F / CH_PER_BLOCK);   // 256 blocks -> 1/CU, 8 waves/CU
    dim3 block(BLOCK);
    qlin_kernel<<<grid, block, 0, stream>>>(x, w_q, scale, bias, out);
}